// Round 1
// 1078.369 us; speedup vs baseline: 1.1404x; 1.1404x over previous
//
#include <hip/hip_runtime.h>
#include <stdint.h>

#define B_   128
#define T_   500
#define C_   700
#define CP_  704          // C padded to 16
#define H_   1024
#define O_   20
#define M_   (T_ * B_)    // 64000 rows, row = t*128 + b
#define KA_  (2 * CP_)    // 1408: A' = [hi | lo]
#define KB_  (3 * CP_)    // 2112: Bt = [hi | hi | lo]
#define SCALE_      256.0f
#define INV_SCALE2_ (1.0f / 65536.0f)
#define MAXD_ 30
#define TT_   20                       // t-rows produced per delay block
#define RR_   (TT_ + MAXD_)            // 50 source rows staged in LDS

typedef _Float16 half8 __attribute__((ext_vector_type(8)));
typedef float    f32x4 __attribute__((ext_vector_type(4)));

// ---------------------------------------------------------------------------
// out[c*R + r] = (c < C) ? in[r*C + c] : 0   (fp32 transpose, zero-pad)
__global__ __launch_bounds__(256) void transpose_pad(
    const float* __restrict__ in, float* __restrict__ out,
    int R, int C, int Cpad) {
  int idx = blockIdx.x * 256 + threadIdx.x;
  if (idx >= Cpad * R) return;
  int c = idx / R;
  int r = idx - c * R;
  out[idx] = (c < C) ? in[(size_t)r * C + c] : 0.0f;
}

// ---------------------------------------------------------------------------
// Bt[n][k]: k in [0,704) -> hi(w*256); [704,1408) -> hi; [1408,2112) -> lo
__global__ __launch_bounds__(256) void bt_prep(
    const float* __restrict__ w_in, _Float16* __restrict__ Bt) {
  int idx = blockIdx.x * 256 + threadIdx.x;   // over H_*KB_
  if (idx >= H_ * KB_) return;
  int n = idx / KB_;
  int k = idx - n * KB_;
  int blk = k / CP_;
  int c = k - blk * CP_;
  float v = (c < C_) ? w_in[(size_t)n * C_ + c] * SCALE_ : 0.0f;
  _Float16 hi = (_Float16)v;
  Bt[idx] = (blk == 2) ? (_Float16)(v - (float)hi) : hi;
}

// ---------------------------------------------------------------------------
// R7: LDS-staged delay gather. One block per (b, 20-step t-tile).
// Source region x[b, t0-30 : t0+20, :] is CONTIGUOUS (x is b-major) and
// 16B-aligned (700*4 % 16 == 0) -> coalesced float4 staging into LDS,
// then the per-channel delay scatter is an LDS read instead of a 31-way
// scattered HBM/L2 read (old kernel: ~64 sub-line fetches per wave).
__global__ __launch_bounds__(512) void delay_split_lds(
    const float* __restrict__ x, const int* __restrict__ delays,
    _Float16* __restrict__ A3) {
  extern __shared__ float xs[];         // RR_ * C_ floats = 140000 B
  __shared__ int sdel[CP_];

  const int b   = blockIdx.x;           // 0..127
  const int t0  = blockIdx.y * TT_;     // 0,20,...,480
  const int tid = threadIdx.x;

  for (int c = tid; c < CP_; c += 512) sdel[c] = (c < C_) ? delays[c] : 0;

  // stage rows [t0-30, t0+20) of sample b; rows with t<0 are zero-filled.
  // zr rows at the front are zero: zr = max(0, 30 - t0). zr*C_ % 4 == 0.
  const int zr = (t0 < MAXD_) ? (MAXD_ - t0) : 0;
  const int zw = zr * C_;
  const float* src = x + ((long)(b * T_ + t0) - MAXD_) * C_;
  for (int i = tid; i < (RR_ * C_) / 4; i += 512) {
    const int w0 = i * 4;
    float4 v = {0.f, 0.f, 0.f, 0.f};
    if (w0 >= zw) v = *(const float4*)(src + w0);
    *(float4*)&xs[w0] = v;
  }
  __syncthreads();

  // produce TT_ output rows: hi at dst[c], lo at dst[CP_+c]
  for (int e = tid; e < TT_ * CP_; e += 512) {
    const int tt = e / CP_;
    const int c  = e - tt * CP_;
    float v = 0.0f;
    if (c < C_) {
      const int lr = tt + MAXD_ - sdel[c];   // 0..49, <zr rows are zeros
      v = xs[lr * C_ + c] * SCALE_;
    }
    const _Float16 hi = (_Float16)v;
    _Float16* dst = A3 + (size_t)((t0 + tt) * B_ + b) * KA_;
    dst[c] = hi;
    dst[CP_ + c] = (_Float16)(v - (float)hi);
  }
}

// ---------------------------------------------------------------------------
__device__ __forceinline__ void gload16(const void* g, const void* l) {
  __builtin_amdgcn_global_load_lds(
      (const __attribute__((address_space(1))) void*)(uintptr_t)g,
      (__attribute__((address_space(3))) void*)(uint32_t)(uintptr_t)l,
      16, 0, 0);
}

// fp16 MFMA GEMM: Cm[M_,H_] = A3[M_,KA_ (hi reused)] x Bt[H_,KB_]^T, *2^-16.
// R7: XCD-aware bijective swizzle so all 8 col-tiles of one A row-panel land
// on ONE XCD (dispatch d -> xcd = d%8; g = xcd*500 + d/8; panel = g/8,
// col = g%8). Old mapping fetched the L3-resident A 8x from HBM per XCD
// (FETCH 1.07 GB); expect ~0.45 GB.
__global__ __launch_bounds__(256) void gemm_split(
    const _Float16* __restrict__ A3, const _Float16* __restrict__ Bt,
    float* __restrict__ Cm) {
  __shared__ __align__(16) _Float16 As[128 * 32];
  __shared__ __align__(16) _Float16 Bs[128 * 32];

  const int tid  = threadIdx.x;
  const int wave = tid >> 6, lane = tid & 63;

  const int d   = blockIdx.y * 8 + blockIdx.x;   // gridDim.x == 8
  const int g   = (d & 7) * (M_ / 128) + (d >> 3);
  const int col0 = (g & 7) * 128;
  const int row0 = (g >> 3) * 128;

  const int q = lane >> 4, r = lane & 15;
  const int wm0 = (wave >> 1) * 64, wn0 = (wave & 1) * 64;

  f32x4 acc[4][4] = {};

  const int pi0 = wave * 2;
  const int srow = lane >> 2;
  const int gch8 = (((lane & 3) ^ ((lane >> 3) & 3))) * 8;

  const int ch8 = (q ^ ((r >> 1) & 3)) * 8;
  int aoff[4], boff[4];
#pragma unroll
  for (int i = 0; i < 4; ++i) {
    aoff[i] = (wm0 + i * 16 + r) * 32 + ch8;
    boff[i] = (wn0 + i * 16 + r) * 32 + ch8;
  }

  const size_t arow0 = (size_t)(row0 + pi0 * 16 + srow);
  const size_t arow1 = arow0 + 16;
  const size_t brow0 = (size_t)(col0 + pi0 * 16 + srow);
  const size_t brow1 = brow0 + 16;

  for (int kb = 0; kb < KB_ / 32; ++kb) {
    const int k0 = kb * 32;
    const int kA = (k0 < KA_) ? k0 : (k0 - KA_);
    __syncthreads();
    gload16(A3 + arow0 * KA_ + kA + gch8, &As[(pi0 + 0) * 512]);
    gload16(A3 + arow1 * KA_ + kA + gch8, &As[(pi0 + 1) * 512]);
    gload16(Bt + brow0 * KB_ + k0 + gch8, &Bs[(pi0 + 0) * 512]);
    gload16(Bt + brow1 * KB_ + k0 + gch8, &Bs[(pi0 + 1) * 512]);
    __syncthreads();

    half8 af[4], bf[4];
#pragma unroll
    for (int i = 0; i < 4; ++i) af[i] = *(const half8*)&As[aoff[i]];
#pragma unroll
    for (int j = 0; j < 4; ++j) bf[j] = *(const half8*)&Bs[boff[j]];
#pragma unroll
    for (int i = 0; i < 4; ++i)
#pragma unroll
      for (int j = 0; j < 4; ++j)
        acc[i][j] = __builtin_amdgcn_mfma_f32_16x16x32_f16(af[i], bf[j],
                                                           acc[i][j], 0, 0, 0);
  }

#pragma unroll
  for (int i = 0; i < 4; ++i) {
    const int mrow = row0 + wm0 + i * 16 + q * 4;
#pragma unroll
    for (int j = 0; j < 4; ++j) {
      const int ncol = col0 + wn0 + j * 16 + r;
      float* cp = Cm + (size_t)mrow * H_ + ncol;
#pragma unroll
      for (int rg = 0; rg < 4; ++rg)
        cp[(size_t)rg * H_] = acc[i][j][rg] * INV_SCALE2_;
    }
  }
}

// ---------------------------------------------------------------------------
// One wave per batch sample; 16 neurons per lane (h = lane*16 + j).
// R6 scalar-built batched gather (no scratch, VGPR-resident) + 4-deep
// register prefetch of Iin (t-loop unrolled x4, rotating explicit float4
// buffer sets).
#define GATHER_LIF_STEP(N0, N1, N2, N3, TCUR)                                 \
  {                                                                           \
    float I[16];                                                              \
    I[0]  = N0.x; I[1]  = N0.y; I[2]  = N0.z; I[3]  = N0.w;                   \
    I[4]  = N1.x; I[5]  = N1.y; I[6]  = N1.z; I[7]  = N1.w;                   \
    I[8]  = N2.x; I[9]  = N2.y; I[10] = N2.z; I[11] = N2.w;                   \
    I[12] = N3.x; I[13] = N3.y; I[14] = N3.z; I[15] = N3.w;                   \
    float io = 0.f;                                                           \
    unsigned long long lm = __ballot(sword != 0u);                            \
    unsigned w = 0u;                                                          \
    int lcur = 0;                                                             \
    while ((lm != 0ull) | (w != 0u)) {                                        \
      int hA, hB, hC, hD;                                                     \
      float sB, sC, sD;                                                       \
      if (w == 0u) {                                                          \
        lcur = (int)__builtin_ctzll(lm); lm &= lm - 1ull;                     \
        w = ((unsigned)__builtin_amdgcn_readlane((int)sword, lcur)) & 0xFFFFu;\
      }                                                                       \
      hA = lcur * 16 + (int)__builtin_ctz(w); w &= w - 1u;                    \
      if (w == 0u && lm != 0ull) {                                            \
        lcur = (int)__builtin_ctzll(lm); lm &= lm - 1ull;                     \
        w = ((unsigned)__builtin_amdgcn_readlane((int)sword, lcur)) & 0xFFFFu;\
      }                                                                       \
      if (w != 0u) { hB = lcur*16 + (int)__builtin_ctz(w); w &= w-1u; sB=1.f;}\
      else         { hB = hA; sB = 0.f; }                                     \
      if (w == 0u && lm != 0ull) {                                            \
        lcur = (int)__builtin_ctzll(lm); lm &= lm - 1ull;                     \
        w = ((unsigned)__builtin_amdgcn_readlane((int)sword, lcur)) & 0xFFFFu;\
      }                                                                       \
      if (w != 0u) { hC = lcur*16 + (int)__builtin_ctz(w); w &= w-1u; sC=1.f;}\
      else         { hC = hA; sC = 0.f; }                                     \
      if (w == 0u && lm != 0ull) {                                            \
        lcur = (int)__builtin_ctzll(lm); lm &= lm - 1ull;                     \
        w = ((unsigned)__builtin_amdgcn_readlane((int)sword, lcur)) & 0xFFFFu;\
      }                                                                       \
      if (w != 0u) { hD = lcur*16 + (int)__builtin_ctz(w); w &= w-1u; sD=1.f;}\
      else         { hD = hA; sD = 0.f; }                                     \
      const float* rA = wrecT + (size_t)hA * H_ + h0;                         \
      const float* rB = wrecT + (size_t)hB * H_ + h0;                         \
      const float* rC = wrecT + (size_t)hC * H_ + h0;                         \
      const float* rD = wrecT + (size_t)hD * H_ + h0;                         \
      float4 wA0 = *(const float4*)(rA + 0),  wA1 = *(const float4*)(rA + 4); \
      float4 wA2 = *(const float4*)(rA + 8),  wA3 = *(const float4*)(rA + 12);\
      float4 wB0 = *(const float4*)(rB + 0),  wB1 = *(const float4*)(rB + 4); \
      float4 wB2 = *(const float4*)(rB + 8),  wB3 = *(const float4*)(rB + 12);\
      float4 wC0 = *(const float4*)(rC + 0),  wC1 = *(const float4*)(rC + 4); \
      float4 wC2 = *(const float4*)(rC + 8),  wC3 = *(const float4*)(rC + 12);\
      float4 wD0 = *(const float4*)(rD + 0),  wD1 = *(const float4*)(rD + 4); \
      float4 wD2 = *(const float4*)(rD + 8),  wD3 = *(const float4*)(rD + 12);\
      const float oA = woutT[(size_t)hA * O_ + olane];                        \
      const float oB = woutT[(size_t)hB * O_ + olane];                        \
      const float oC = woutT[(size_t)hC * O_ + olane];                        \
      const float oD = woutT[(size_t)hD * O_ + olane];                        \
      I[0] += wA0.x; I[1] += wA0.y; I[2]  += wA0.z; I[3]  += wA0.w;           \
      I[4] += wA1.x; I[5] += wA1.y; I[6]  += wA1.z; I[7]  += wA1.w;           \
      I[8] += wA2.x; I[9] += wA2.y; I[10] += wA2.z; I[11] += wA2.w;           \
      I[12]+= wA3.x; I[13]+= wA3.y; I[14] += wA3.z; I[15] += wA3.w;           \
      io += oA;                                                               \
      I[0]  = fmaf(sB, wB0.x, I[0]);  I[1]  = fmaf(sB, wB0.y, I[1]);          \
      I[2]  = fmaf(sB, wB0.z, I[2]);  I[3]  = fmaf(sB, wB0.w, I[3]);          \
      I[4]  = fmaf(sB, wB1.x, I[4]);  I[5]  = fmaf(sB, wB1.y, I[5]);          \
      I[6]  = fmaf(sB, wB1.z, I[6]);  I[7]  = fmaf(sB, wB1.w, I[7]);          \
      I[8]  = fmaf(sB, wB2.x, I[8]);  I[9]  = fmaf(sB, wB2.y, I[9]);          \
      I[10] = fmaf(sB, wB2.z, I[10]); I[11] = fmaf(sB, wB2.w, I[11]);         \
      I[12] = fmaf(sB, wB3.x, I[12]); I[13] = fmaf(sB, wB3.y, I[13]);         \
      I[14] = fmaf(sB, wB3.z, I[14]); I[15] = fmaf(sB, wB3.w, I[15]);         \
      io = fmaf(sB, oB, io);                                                  \
      I[0]  = fmaf(sC, wC0.x, I[0]);  I[1]  = fmaf(sC, wC0.y, I[1]);          \
      I[2]  = fmaf(sC, wC0.z, I[2]);  I[3]  = fmaf(sC, wC0.w, I[3]);          \
      I[4]  = fmaf(sC, wC1.x, I[4]);  I[5]  = fmaf(sC, wC1.y, I[5]);          \
      I[6]  = fmaf(sC, wC1.z, I[6]);  I[7]  = fmaf(sC, wC1.w, I[7]);          \
      I[8]  = fmaf(sC, wC2.x, I[8]);  I[9]  = fmaf(sC, wC2.y, I[9]);          \
      I[10] = fmaf(sC, wC2.z, I[10]); I[11] = fmaf(sC, wC2.w, I[11]);         \
      I[12] = fmaf(sC, wC3.x, I[12]); I[13] = fmaf(sC, wC3.y, I[13]);         \
      I[14] = fmaf(sC, wC3.z, I[14]); I[15] = fmaf(sC, wC3.w, I[15]);         \
      io = fmaf(sC, oC, io);                                                  \
      I[0]  = fmaf(sD, wD0.x, I[0]);  I[1]  = fmaf(sD, wD0.y, I[1]);          \
      I[2]  = fmaf(sD, wD0.z, I[2]);  I[3]  = fmaf(sD, wD0.w, I[3]);          \
      I[4]  = fmaf(sD, wD1.x, I[4]);  I[5]  = fmaf(sD, wD1.y, I[5]);          \
      I[6]  = fmaf(sD, wD1.z, I[6]);  I[7]  = fmaf(sD, wD1.w, I[7]);          \
      I[8]  = fmaf(sD, wD2.x, I[8]);  I[9]  = fmaf(sD, wD2.y, I[9]);          \
      I[10] = fmaf(sD, wD2.z, I[10]); I[11] = fmaf(sD, wD2.w, I[11]);         \
      I[12] = fmaf(sD, wD3.x, I[12]); I[13] = fmaf(sD, wD3.y, I[13]);         \
      I[14] = fmaf(sD, wD3.z, I[14]); I[15] = fmaf(sD, wD3.w, I[15]);         \
      io = fmaf(sD, oD, io);                                                  \
    }                                                                         \
    {                                                                         \
      const int tp = ((TCUR) + 4 <= T_ - 1) ? (TCUR) + 4 : (T_ - 1);          \
      const float* nb = base + (size_t)tp * (B_ * H_);                        \
      N0 = *(const float4*)(nb + 0);                                          \
      N1 = *(const float4*)(nb + 4);                                          \
      N2 = *(const float4*)(nb + 8);                                          \
      N3 = *(const float4*)(nb + 12);                                         \
    }                                                                         \
    vo = bo * vo + (1.0f - bo) * io;                                          \
    osum += vo;                                                               \
    unsigned swordn = 0u;                                                     \
    _Pragma("unroll")                                                         \
    for (int j = 0; j < 16; ++j) {                                            \
      const float vg = (sword & (1u << j)) ? 0.f : v[j];                      \
      const float vn = al * vg + al1 * (I[j] - av[j]);                        \
      av[j] = rh * av[j] + rh1 * fmaf(ba, vn, (vn > 1.0f) ? 1.0f : 0.0f);     \
      v[j] = vn;                                                              \
      swordn |= (vn > 1.0f) ? (1u << j) : 0u;                                 \
    }                                                                         \
    sword = swordn;                                                           \
  }

__global__ __launch_bounds__(64, 1) void recurrent_w(
    const float* __restrict__ Iin,   // [M_][H_], row = t*128 + b
    const float* __restrict__ wrecT, // [H_][H_]  wrecT[h'][h] = w_rec[h][h']
    const float* __restrict__ woutT, // [H_][O_]  woutT[h][o]  = w_out[o][h]
    const float* __restrict__ alpha, const float* __restrict__ rho,
    const float* __restrict__ beta_a, const float* __restrict__ beta_out,
    float* __restrict__ out) {
  const int b = blockIdx.x;
  const int lane = threadIdx.x;
  const int h0 = lane * 16;

  float v[16], av[16];
#pragma unroll
  for (int j = 0; j < 16; ++j) { v[j] = 0.f; av[j] = 0.f; }
  unsigned sword = 0u;   // bit j = neuron h0+j spiked at previous step

  const float al = alpha[h0], al1 = 1.0f - al;
  const float rh = rho[h0],   rh1 = 1.0f - rh;
  const float ba = beta_a[h0];

  const int olane = (lane < O_) ? lane : 0;
  float bo = 0.f, vo = 0.f, osum = 0.f;
  if (lane < O_) bo = beta_out[lane];

  const float* base = Iin + (size_t)b * H_ + h0;

  // prime 4-deep prefetch pipeline: buffers for t = 0,1,2,3
  float4 pA0, pA1, pA2, pA3, pB0, pB1, pB2, pB3;
  float4 pC0, pC1, pC2, pC3, pD0, pD1, pD2, pD3;
  {
    const float* p0 = base + (size_t)0 * (B_ * H_);
    const float* p1 = base + (size_t)1 * (B_ * H_);
    const float* p2 = base + (size_t)2 * (B_ * H_);
    const float* p3 = base + (size_t)3 * (B_ * H_);
    pA0 = *(const float4*)(p0 + 0); pA1 = *(const float4*)(p0 + 4);
    pA2 = *(const float4*)(p0 + 8); pA3 = *(const float4*)(p0 + 12);
    pB0 = *(const float4*)(p1 + 0); pB1 = *(const float4*)(p1 + 4);
    pB2 = *(const float4*)(p1 + 8); pB3 = *(const float4*)(p1 + 12);
    pC0 = *(const float4*)(p2 + 0); pC1 = *(const float4*)(p2 + 4);
    pC2 = *(const float4*)(p2 + 8); pC3 = *(const float4*)(p2 + 12);
    pD0 = *(const float4*)(p3 + 0); pD1 = *(const float4*)(p3 + 4);
    pD2 = *(const float4*)(p3 + 8); pD3 = *(const float4*)(p3 + 12);
  }

  for (int k = 0; k < T_ / 4; ++k) {
    const int t0 = k * 4;
    GATHER_LIF_STEP(pA0, pA1, pA2, pA3, t0 + 0)
    GATHER_LIF_STEP(pB0, pB1, pB2, pB3, t0 + 1)
    GATHER_LIF_STEP(pC0, pC1, pC2, pC3, t0 + 2)
    GATHER_LIF_STEP(pD0, pD1, pD2, pD3, t0 + 3)
  }

  // epilogue: readout contribution of the final spike set S(T-1)
  {
    float io = 0.f;
    unsigned long long lm = __ballot(sword != 0u);
    while (lm != 0ull) {
      const int l = (int)__builtin_ctzll(lm); lm &= lm - 1ull;
      unsigned w = ((unsigned)__builtin_amdgcn_readlane((int)sword, l)) & 0xFFFFu;
      while (w != 0u) {
        const int j = (int)__builtin_ctz(w); w &= w - 1u;
        io += woutT[(size_t)(l * 16 + j) * O_ + olane];
      }
    }
    vo = bo * vo + (1.0f - bo) * io;
    osum += vo;
  }

  if (lane < O_) out[(size_t)b * O_ + lane] = osum / (float)T_;
}

// ---------------------------------------------------------------------------
extern "C" void kernel_launch(void* const* d_in, const int* in_sizes, int n_in,
                              void* d_out, int out_size, void* d_ws, size_t ws_size,
                              hipStream_t stream) {
  const float* x        = (const float*)d_in[0];
  const int*   delays   = (const int*)d_in[1];
  const float* w_in     = (const float*)d_in[2];
  const float* w_rec    = (const float*)d_in[3];
  const float* w_out    = (const float*)d_in[4];
  const float* alpha    = (const float*)d_in[5];
  const float* rho      = (const float*)d_in[6];
  const float* beta_a   = (const float*)d_in[7];
  const float* beta_out = (const float*)d_in[8];

  float* ws    = (float*)d_ws;
  float* wrecT = ws;                                 // H*H fp32
  float* woutT = wrecT + (size_t)H_ * H_;            // H*O fp32
  float* Iin   = woutT + (size_t)H_ * O_;            // M*H fp32
  _Float16* A3 = (_Float16*)(Iin + (size_t)M_ * H_); // M*KA fp16
  _Float16* Bt = A3 + (size_t)M_ * KA_;              // H*KB fp16
  float* out   = (float*)d_out;

  transpose_pad<<<(H_ * H_) / 256, 256, 0, stream>>>(w_rec, wrecT, H_, H_, H_);
  transpose_pad<<<(H_ * O_) / 256, 256, 0, stream>>>(w_out, woutT, O_, H_, H_);
  bt_prep<<<(H_ * KB_) / 256, 256, 0, stream>>>(w_in, Bt);

  dim3 gd(B_, T_ / TT_);   // (128, 25)
  delay_split_lds<<<gd, 512, RR_ * C_ * sizeof(float), stream>>>(x, delays, A3);

  dim3 g(H_ / 128, M_ / 128);
  gemm_split<<<g, 256, 0, stream>>>(A3, Bt, Iin);

  recurrent_w<<<B_, 64, 0, stream>>>(Iin, wrecT, woutT,
                                     alpha, rho, beta_a, beta_out, out);
}

// Round 2
// 961.016 us; speedup vs baseline: 1.2797x; 1.1221x over previous
//
#include <hip/hip_runtime.h>
#include <stdint.h>

#define B_   128
#define T_   500
#define C_   700
#define CP_  704          // C padded to 16
#define H_   1024
#define O_   20
#define M_   (T_ * B_)    // 64000 rows, row = t*128 + b
#define KA_  (2 * CP_)    // 1408: A' = [hi | lo]
#define KB_  (3 * CP_)    // 2112: Bt = [hi | hi | lo]
#define SCALE_      256.0f
#define INV_SCALE2_ (1.0f / 65536.0f)
#define MAXD_ 30
#define TT_   20                       // t-rows produced per delay block
#define RR_   (TT_ + MAXD_)            // 50 source rows staged in LDS
#define CS_   352                      // channels per delay block (2-way split)
#define LSTR_ 353                      // LDS row stride (anti-bank-conflict)

typedef _Float16 half8 __attribute__((ext_vector_type(8)));
typedef float    f32x4 __attribute__((ext_vector_type(4)));

// ---------------------------------------------------------------------------
// out[c*R + r] = (c < C) ? in[r*C + c] : 0   (fp32 transpose, zero-pad)
__global__ __launch_bounds__(256) void transpose_pad(
    const float* __restrict__ in, float* __restrict__ out,
    int R, int C, int Cpad) {
  int idx = blockIdx.x * 256 + threadIdx.x;
  if (idx >= Cpad * R) return;
  int c = idx / R;
  int r = idx - c * R;
  out[idx] = (c < C) ? in[(size_t)r * C + c] : 0.0f;
}

// ---------------------------------------------------------------------------
// Bt[n][k]: k in [0,704) -> hi(w*256); [704,1408) -> hi; [1408,2112) -> lo
__global__ __launch_bounds__(256) void bt_prep(
    const float* __restrict__ w_in, _Float16* __restrict__ Bt) {
  int idx = blockIdx.x * 256 + threadIdx.x;   // over H_*KB_
  if (idx >= H_ * KB_) return;
  int n = idx / KB_;
  int k = idx - n * KB_;
  int blk = k / CP_;
  int c = k - blk * CP_;
  float v = (c < C_) ? w_in[(size_t)n * C_ + c] * SCALE_ : 0.0f;
  _Float16 hi = (_Float16)v;
  Bt[idx] = (blk == 2) ? (_Float16)(v - (float)hi) : hi;
}

// ---------------------------------------------------------------------------
// R8: channel-split LDS delay gather. Block = (b, 20-step t-tile, 352-ch half).
// LDS 50x353 fp32 = 70.6 KB -> 2 blocks/CU (R7's 140 KB forced 1/CU, no
// overlap). Stride 353: 352 is 0 mod 32, so bank would depend only on
// channel%4*8 -> 16-way conflict; +1 word makes bank = (lr + 8cc + j) & 31
// with lr randomized by per-channel delay. Output: 8 channels/thread ->
// two half8 (16 B) stores instead of sixteen 2-B stores.
__global__ __launch_bounds__(512) void delay_split_lds(
    const float* __restrict__ x, const int* __restrict__ delays,
    _Float16* __restrict__ A3) {
  extern __shared__ float xs[];          // [RR_][LSTR_] floats = 70600 B
  __shared__ int sdel[CS_];

  const int b   = blockIdx.x;            // 0..127
  const int t0  = blockIdx.y * TT_;      // 0,20,...,480
  const int c0  = blockIdx.z * CS_;      // 0 or 352
  const int tid = threadIdx.x;

  for (int c = tid; c < CS_; c += 512) {
    const int cc = c0 + c;
    sdel[c] = (cc < C_) ? delays[cc] : 0;
  }

  // stage rows [t0-30, t0+20) x channels [c0, c0+352); t<0 rows zero-filled.
  const int zr = (t0 < MAXD_) ? (MAXD_ - t0) : 0;
  const float* srcb = x + ((long)(b * T_ + t0) - MAXD_) * C_ + c0;
  for (int i = tid; i < RR_ * (CS_ / 4); i += 512) {
    const int r  = i / (CS_ / 4);
    const int q4 = (i - r * (CS_ / 4)) * 4;
    float4 v = {0.f, 0.f, 0.f, 0.f};
    if (r >= zr && c0 + q4 < C_)       // 700 % 4 == 0: chunks never straddle
      v = *(const float4*)(srcb + (long)r * C_ + q4);
    *(float4*)&xs[r * LSTR_ + q4] = v;
  }
  __syncthreads();

  // produce TT_ rows x 352 channels: 8 ch/thread, half8 stores for hi and lo
  for (int e = tid; e < TT_ * (CS_ / 8); e += 512) {
    const int tt = e / (CS_ / 8);
    const int cl = (e - tt * (CS_ / 8)) * 8;
    half8 hv, lv;
#pragma unroll
    for (int j = 0; j < 8; ++j) {
      const int c = cl + j;
      float vv = 0.f;
      if (c0 + c < C_)
        vv = xs[(tt + MAXD_ - sdel[c]) * LSTR_ + c] * SCALE_;
      const _Float16 hi = (_Float16)vv;
      hv[j] = hi;
      lv[j] = (_Float16)(vv - (float)hi);
    }
    _Float16* dst = A3 + (size_t)((t0 + tt) * B_ + b) * KA_ + c0 + cl;
    *(half8*)dst = hv;
    *((half8*)(dst + CP_)) = lv;
  }
}

// ---------------------------------------------------------------------------
__device__ __forceinline__ void gload16(const void* g, const void* l) {
  __builtin_amdgcn_global_load_lds(
      (const __attribute__((address_space(1))) void*)(uintptr_t)g,
      (__attribute__((address_space(3))) void*)(uint32_t)(uintptr_t)l,
      16, 0, 0);
}

// fp16 MFMA GEMM: Cm[M_,H_] = A3[M_,KA_ (hi reused)] x Bt[H_,KB_]^T, *2^-16.
// XCD-aware bijective swizzle (R7: FETCH 1.07 GB -> 239 MB, confirmed).
__global__ __launch_bounds__(256) void gemm_split(
    const _Float16* __restrict__ A3, const _Float16* __restrict__ Bt,
    float* __restrict__ Cm) {
  __shared__ __align__(16) _Float16 As[128 * 32];
  __shared__ __align__(16) _Float16 Bs[128 * 32];

  const int tid  = threadIdx.x;
  const int wave = tid >> 6, lane = tid & 63;

  const int d   = blockIdx.y * 8 + blockIdx.x;   // gridDim.x == 8
  const int g   = (d & 7) * (M_ / 128) + (d >> 3);
  const int col0 = (g & 7) * 128;
  const int row0 = (g >> 3) * 128;

  const int q = lane >> 4, r = lane & 15;
  const int wm0 = (wave >> 1) * 64, wn0 = (wave & 1) * 64;

  f32x4 acc[4][4] = {};

  const int pi0 = wave * 2;
  const int srow = lane >> 2;
  const int gch8 = (((lane & 3) ^ ((lane >> 3) & 3))) * 8;

  const int ch8 = (q ^ ((r >> 1) & 3)) * 8;
  int aoff[4], boff[4];
#pragma unroll
  for (int i = 0; i < 4; ++i) {
    aoff[i] = (wm0 + i * 16 + r) * 32 + ch8;
    boff[i] = (wn0 + i * 16 + r) * 32 + ch8;
  }

  const size_t arow0 = (size_t)(row0 + pi0 * 16 + srow);
  const size_t arow1 = arow0 + 16;
  const size_t brow0 = (size_t)(col0 + pi0 * 16 + srow);
  const size_t brow1 = brow0 + 16;

  for (int kb = 0; kb < KB_ / 32; ++kb) {
    const int k0 = kb * 32;
    const int kA = (k0 < KA_) ? k0 : (k0 - KA_);
    __syncthreads();
    gload16(A3 + arow0 * KA_ + kA + gch8, &As[(pi0 + 0) * 512]);
    gload16(A3 + arow1 * KA_ + kA + gch8, &As[(pi0 + 1) * 512]);
    gload16(Bt + brow0 * KB_ + k0 + gch8, &Bs[(pi0 + 0) * 512]);
    gload16(Bt + brow1 * KB_ + k0 + gch8, &Bs[(pi0 + 1) * 512]);
    __syncthreads();

    half8 af[4], bf[4];
#pragma unroll
    for (int i = 0; i < 4; ++i) af[i] = *(const half8*)&As[aoff[i]];
#pragma unroll
    for (int j = 0; j < 4; ++j) bf[j] = *(const half8*)&Bs[boff[j]];
#pragma unroll
    for (int i = 0; i < 4; ++i)
#pragma unroll
      for (int j = 0; j < 4; ++j)
        acc[i][j] = __builtin_amdgcn_mfma_f32_16x16x32_f16(af[i], bf[j],
                                                           acc[i][j], 0, 0, 0);
  }

#pragma unroll
  for (int i = 0; i < 4; ++i) {
    const int mrow = row0 + wm0 + i * 16 + q * 4;
#pragma unroll
    for (int j = 0; j < 4; ++j) {
      const int ncol = col0 + wn0 + j * 16 + r;
      float* cp = Cm + (size_t)mrow * H_ + ncol;
#pragma unroll
      for (int rg = 0; rg < 4; ++rg)
        cp[(size_t)rg * H_] = acc[i][j][rg] * INV_SCALE2_;
    }
  }
}

// ---------------------------------------------------------------------------
// R8: 4-wave column split. 256 threads per batch sample, 4 neurons per
// thread (h = tid*4 + j). Per step, the 1024-bit spike set is exchanged via
// a double-buffered 256-byte LDS array + one barrier; each lane rebuilds
// sword with the SAME layout as the 1-wave kernel (lane l <-> neurons
// [l*16, l*16+16)), so the proven readlane/ctz scan is unchanged. Gather
// FMA per lane drops 16 cols -> 4 cols; wrecT row loads 64 B -> 16 B/lane.
#define GATHER_LIF_STEP(NR, TCUR)                                             \
  {                                                                           \
    float Iv[4];                                                              \
    Iv[0] = NR.x; Iv[1] = NR.y; Iv[2] = NR.z; Iv[3] = NR.w;                   \
    float io = 0.f;                                                           \
    unsigned long long lm = __ballot(sword != 0u);                            \
    unsigned w = 0u;                                                          \
    int lcur = 0;                                                             \
    while ((lm != 0ull) | (w != 0u)) {                                        \
      int hA, hB, hC, hD;                                                     \
      float sB, sC, sD;                                                       \
      if (w == 0u) {                                                          \
        lcur = (int)__builtin_ctzll(lm); lm &= lm - 1ull;                     \
        w = ((unsigned)__builtin_amdgcn_readlane((int)sword, lcur)) & 0xFFFFu;\
      }                                                                       \
      hA = lcur * 16 + (int)__builtin_ctz(w); w &= w - 1u;                    \
      if (w == 0u && lm != 0ull) {                                            \
        lcur = (int)__builtin_ctzll(lm); lm &= lm - 1ull;                     \
        w = ((unsigned)__builtin_amdgcn_readlane((int)sword, lcur)) & 0xFFFFu;\
      }                                                                       \
      if (w != 0u) { hB = lcur*16 + (int)__builtin_ctz(w); w &= w-1u; sB=1.f;}\
      else         { hB = hA; sB = 0.f; }                                     \
      if (w == 0u && lm != 0ull) {                                            \
        lcur = (int)__builtin_ctzll(lm); lm &= lm - 1ull;                     \
        w = ((unsigned)__builtin_amdgcn_readlane((int)sword, lcur)) & 0xFFFFu;\
      }                                                                       \
      if (w != 0u) { hC = lcur*16 + (int)__builtin_ctz(w); w &= w-1u; sC=1.f;}\
      else         { hC = hA; sC = 0.f; }                                     \
      if (w == 0u && lm != 0ull) {                                            \
        lcur = (int)__builtin_ctzll(lm); lm &= lm - 1ull;                     \
        w = ((unsigned)__builtin_amdgcn_readlane((int)sword, lcur)) & 0xFFFFu;\
      }                                                                       \
      if (w != 0u) { hD = lcur*16 + (int)__builtin_ctz(w); w &= w-1u; sD=1.f;}\
      else         { hD = hA; sD = 0.f; }                                     \
      const float4 wA = *(const float4*)(wrecT + (size_t)hA * H_ + h0);       \
      const float4 wB = *(const float4*)(wrecT + (size_t)hB * H_ + h0);       \
      const float4 wC = *(const float4*)(wrecT + (size_t)hC * H_ + h0);       \
      const float4 wD = *(const float4*)(wrecT + (size_t)hD * H_ + h0);       \
      const float oA = woutT[(size_t)hA * O_ + olane];                        \
      const float oB = woutT[(size_t)hB * O_ + olane];                        \
      const float oC = woutT[(size_t)hC * O_ + olane];                        \
      const float oD = woutT[(size_t)hD * O_ + olane];                        \
      Iv[0] += wA.x; Iv[1] += wA.y; Iv[2] += wA.z; Iv[3] += wA.w;             \
      io += oA;                                                               \
      Iv[0] = fmaf(sB, wB.x, Iv[0]); Iv[1] = fmaf(sB, wB.y, Iv[1]);           \
      Iv[2] = fmaf(sB, wB.z, Iv[2]); Iv[3] = fmaf(sB, wB.w, Iv[3]);           \
      io = fmaf(sB, oB, io);                                                  \
      Iv[0] = fmaf(sC, wC.x, Iv[0]); Iv[1] = fmaf(sC, wC.y, Iv[1]);           \
      Iv[2] = fmaf(sC, wC.z, Iv[2]); Iv[3] = fmaf(sC, wC.w, Iv[3]);           \
      io = fmaf(sC, oC, io);                                                  \
      Iv[0] = fmaf(sD, wD.x, Iv[0]); Iv[1] = fmaf(sD, wD.y, Iv[1]);           \
      Iv[2] = fmaf(sD, wD.z, Iv[2]); Iv[3] = fmaf(sD, wD.w, Iv[3]);           \
      io = fmaf(sD, oD, io);                                                  \
    }                                                                         \
    {                                                                         \
      const int tp = ((TCUR) + 4 <= T_ - 1) ? (TCUR) + 4 : (T_ - 1);          \
      NR = *(const float4*)(base + (size_t)tp * (B_ * H_));                   \
    }                                                                         \
    vo = bo * vo + (1.0f - bo) * io;                                          \
    osum += vo;                                                               \
    unsigned nib = 0u;                                                        \
    _Pragma("unroll")                                                         \
    for (int j = 0; j < 4; ++j) {                                             \
      const float vg = (pnib & (1u << j)) ? 0.f : vv[j];                      \
      const float vn = al * vg + al1 * (Iv[j] - av[j]);                       \
      av[j] = rh * av[j] + rh1 * fmaf(ba, vn, (vn > 1.0f) ? 1.0f : 0.0f);     \
      vv[j] = vn;                                                             \
      nib |= (vn > 1.0f) ? (1u << j) : 0u;                                    \
    }                                                                         \
    pnib = nib;                                                               \
    spb[nbuf][tid] = (unsigned char)nib;                                      \
    __syncthreads();                                                          \
    {                                                                         \
      const unsigned w32 = *(const unsigned*)&spb[nbuf][lane * 4];            \
      sword = (w32 & 0xFu) | ((w32 >> 4) & 0xF0u) |                           \
              ((w32 >> 8) & 0xF00u) | ((w32 >> 12) & 0xF000u);                \
    }                                                                         \
    nbuf ^= 1;                                                                \
  }

__global__ __launch_bounds__(256, 1) void recurrent_w(
    const float* __restrict__ Iin,   // [M_][H_], row = t*128 + b
    const float* __restrict__ wrecT, // [H_][H_]  wrecT[h'][h] = w_rec[h][h']
    const float* __restrict__ woutT, // [H_][O_]  woutT[h][o]  = w_out[o][h]
    const float* __restrict__ alpha, const float* __restrict__ rho,
    const float* __restrict__ beta_a, const float* __restrict__ beta_out,
    float* __restrict__ out) {
  const int b    = blockIdx.x;
  const int tid  = threadIdx.x;     // 0..255
  const int lane = tid & 63;
  const int h0   = tid * 4;         // 4 columns per thread

  __shared__ unsigned char spb[2][256];   // double-buffered spike nibbles

  float vv[4], av[4];
#pragma unroll
  for (int j = 0; j < 4; ++j) { vv[j] = 0.f; av[j] = 0.f; }
  unsigned sword = 0u;   // full-bitmap slice: bit j = neuron lane*16+j @ prev
  unsigned pnib  = 0u;   // this thread's own 4 prev-spike bits
  int nbuf = 0;

  const float al = alpha[h0], al1 = 1.0f - al;
  const float rh = rho[h0],   rh1 = 1.0f - rh;
  const float ba = beta_a[h0];

  const int olane = (tid < O_) ? tid : 0;
  float bo = 0.f, vo = 0.f, osum = 0.f;
  if (tid < O_) bo = beta_out[tid];

  const float* base = Iin + (size_t)b * H_ + h0;

  // prime 4-deep prefetch pipeline: one float4 per t = 0,1,2,3
  float4 pA = *(const float4*)(base + (size_t)0 * (B_ * H_));
  float4 pB = *(const float4*)(base + (size_t)1 * (B_ * H_));
  float4 pC = *(const float4*)(base + (size_t)2 * (B_ * H_));
  float4 pD = *(const float4*)(base + (size_t)3 * (B_ * H_));

  for (int k = 0; k < T_ / 4; ++k) {
    const int t0 = k * 4;
    GATHER_LIF_STEP(pA, t0 + 0)
    GATHER_LIF_STEP(pB, t0 + 1)
    GATHER_LIF_STEP(pC, t0 + 2)
    GATHER_LIF_STEP(pD, t0 + 3)
  }

  // epilogue: readout contribution of the final spike set S(T-1)
  {
    float io = 0.f;
    unsigned long long lm = __ballot(sword != 0u);
    while (lm != 0ull) {
      const int l = (int)__builtin_ctzll(lm); lm &= lm - 1ull;
      unsigned w = ((unsigned)__builtin_amdgcn_readlane((int)sword, l)) & 0xFFFFu;
      while (w != 0u) {
        const int j = (int)__builtin_ctz(w); w &= w - 1u;
        io += woutT[(size_t)(l * 16 + j) * O_ + olane];
      }
    }
    vo = bo * vo + (1.0f - bo) * io;
    osum += vo;
  }

  if (tid < O_) out[(size_t)b * O_ + tid] = osum / (float)T_;
}

// ---------------------------------------------------------------------------
extern "C" void kernel_launch(void* const* d_in, const int* in_sizes, int n_in,
                              void* d_out, int out_size, void* d_ws, size_t ws_size,
                              hipStream_t stream) {
  const float* x        = (const float*)d_in[0];
  const int*   delays   = (const int*)d_in[1];
  const float* w_in     = (const float*)d_in[2];
  const float* w_rec    = (const float*)d_in[3];
  const float* w_out    = (const float*)d_in[4];
  const float* alpha    = (const float*)d_in[5];
  const float* rho      = (const float*)d_in[6];
  const float* beta_a   = (const float*)d_in[7];
  const float* beta_out = (const float*)d_in[8];

  float* ws    = (float*)d_ws;
  float* wrecT = ws;                                 // H*H fp32
  float* woutT = wrecT + (size_t)H_ * H_;            // H*O fp32
  float* Iin   = woutT + (size_t)H_ * O_;            // M*H fp32
  _Float16* A3 = (_Float16*)(Iin + (size_t)M_ * H_); // M*KA fp16
  _Float16* Bt = A3 + (size_t)M_ * KA_;              // H*KB fp16
  float* out   = (float*)d_out;

  transpose_pad<<<(H_ * H_) / 256, 256, 0, stream>>>(w_rec, wrecT, H_, H_, H_);
  transpose_pad<<<(H_ * O_) / 256, 256, 0, stream>>>(w_out, woutT, O_, H_, H_);
  bt_prep<<<(H_ * KB_) / 256, 256, 0, stream>>>(w_in, Bt);

  dim3 gd(B_, T_ / TT_, 2);   // (128, 25, 2)
  delay_split_lds<<<gd, 512, RR_ * LSTR_ * sizeof(float), stream>>>(x, delays, A3);

  dim3 g(H_ / 128, M_ / 128);
  gemm_split<<<g, 256, 0, stream>>>(A3, Bt, Iin);

  recurrent_w<<<B_, 256, 0, stream>>>(Iin, wrecT, woutT,
                                      alpha, rho, beta_a, beta_out, out);
}

// Round 3
// 896.190 us; speedup vs baseline: 1.3722x; 1.0723x over previous
//
#include <hip/hip_runtime.h>
#include <stdint.h>

#define B_   128
#define T_   500
#define C_   700
#define CP_  704          // C padded to 16
#define H_   1024
#define O_   20
#define M_   (T_ * B_)    // 64000 rows, row = t*128 + b
#define KA_  (2 * CP_)    // 1408: A' = [hi | lo]
#define KB_  (3 * CP_)    // 2112: Bt = [hi | hi | lo]
#define NKSTEP_ (KB_ / 64)   // 33 K-steps of 64
#define SCALE_      256.0f
#define INV_SCALE2_ (1.0f / 65536.0f)
#define MAXD_ 30
#define TT_   20                       // t-rows produced per delay block
#define RR_   (TT_ + MAXD_)            // 50 source rows staged in LDS
#define CS_   352                      // channels per delay block (2-way split)
#define LSTR_ 353                      // LDS row stride (anti-bank-conflict)

typedef _Float16 half8 __attribute__((ext_vector_type(8)));
typedef float    f32x4 __attribute__((ext_vector_type(4)));

// ---------------------------------------------------------------------------
// out[c*R + r] = (c < C) ? in[r*C + c] : 0   (fp32 transpose, zero-pad)
__global__ __launch_bounds__(256) void transpose_pad(
    const float* __restrict__ in, float* __restrict__ out,
    int R, int C, int Cpad) {
  int idx = blockIdx.x * 256 + threadIdx.x;
  if (idx >= Cpad * R) return;
  int c = idx / R;
  int r = idx - c * R;
  out[idx] = (c < C) ? in[(size_t)r * C + c] : 0.0f;
}

// ---------------------------------------------------------------------------
// Bt[n][k]: k in [0,704) -> hi(w*256); [704,1408) -> hi; [1408,2112) -> lo
__global__ __launch_bounds__(256) void bt_prep(
    const float* __restrict__ w_in, _Float16* __restrict__ Bt) {
  int idx = blockIdx.x * 256 + threadIdx.x;   // over H_*KB_
  if (idx >= H_ * KB_) return;
  int n = idx / KB_;
  int k = idx - n * KB_;
  int blk = k / CP_;
  int c = k - blk * CP_;
  float v = (c < C_) ? w_in[(size_t)n * C_ + c] * SCALE_ : 0.0f;
  _Float16 hi = (_Float16)v;
  Bt[idx] = (blk == 2) ? (_Float16)(v - (float)hi) : hi;
}

// ---------------------------------------------------------------------------
// R8 delay gather (unchanged this round, for attribution).
__global__ __launch_bounds__(512) void delay_split_lds(
    const float* __restrict__ x, const int* __restrict__ delays,
    _Float16* __restrict__ A3) {
  extern __shared__ float xs[];          // [RR_][LSTR_] floats = 70600 B
  __shared__ int sdel[CS_];

  const int b   = blockIdx.x;            // 0..127
  const int t0  = blockIdx.y * TT_;      // 0,20,...,480
  const int c0  = blockIdx.z * CS_;      // 0 or 352
  const int tid = threadIdx.x;

  for (int c = tid; c < CS_; c += 512) {
    const int cc = c0 + c;
    sdel[c] = (cc < C_) ? delays[cc] : 0;
  }

  const int zr = (t0 < MAXD_) ? (MAXD_ - t0) : 0;
  const float* srcb = x + ((long)(b * T_ + t0) - MAXD_) * C_ + c0;
  for (int i = tid; i < RR_ * (CS_ / 4); i += 512) {
    const int r  = i / (CS_ / 4);
    const int q4 = (i - r * (CS_ / 4)) * 4;
    float4 v = {0.f, 0.f, 0.f, 0.f};
    if (r >= zr && c0 + q4 < C_)
      v = *(const float4*)(srcb + (long)r * C_ + q4);
    *(float4*)&xs[r * LSTR_ + q4] = v;
  }
  __syncthreads();

  for (int e = tid; e < TT_ * (CS_ / 8); e += 512) {
    const int tt = e / (CS_ / 8);
    const int cl = (e - tt * (CS_ / 8)) * 8;
    half8 hv, lv;
#pragma unroll
    for (int j = 0; j < 8; ++j) {
      const int c = cl + j;
      float vv = 0.f;
      if (c0 + c < C_)
        vv = xs[(tt + MAXD_ - sdel[c]) * LSTR_ + c] * SCALE_;
      const _Float16 hi = (_Float16)vv;
      hv[j] = hi;
      lv[j] = (_Float16)(vv - (float)hi);
    }
    _Float16* dst = A3 + (size_t)((t0 + tt) * B_ + b) * KA_ + c0 + cl;
    *(half8*)dst = hv;
    *((half8*)(dst + CP_)) = lv;
  }
}

// ---------------------------------------------------------------------------
__device__ __forceinline__ void gload16(const void* g, const void* l) {
  __builtin_amdgcn_global_load_lds(
      (const __attribute__((address_space(1))) void*)(uintptr_t)g,
      (__attribute__((address_space(3))) void*)(uint32_t)(uintptr_t)l,
      16, 0, 0);
}

// ---------------------------------------------------------------------------
// R9: 256x256-tile GEMM, BK=64, 8 waves (2Mx4N), 512 threads, 128 KiB LDS
// double-buffer, counted vmcnt(8) (never 0 in main loop), raw s_barrier,
// T2 XOR-swizzle (slot = chunk ^ (row&7), pre-swizzled global source so
// global_load_lds stays linear-dest), setprio around MFMA clusters.
// Ledger (2 barriers / 64-K step):
//   iter k: STAGE(k+1)->buf[(k+1)&1]   [safe: last read in iter k-1, B2-fenced]
//           vmcnt(8)                   [stage(k) landed, k+1's 8 in flight]
//           B1 [all waves' stage(k) landed]
//           ds_read+MFMA ks0, ks1 from buf[k&1]
//           B2 [all waves done reading buf[k&1]]
__global__ __launch_bounds__(512, 1) void gemm_split(
    const _Float16* __restrict__ A3, const _Float16* __restrict__ Bt,
    float* __restrict__ Cm) {
  extern __shared__ __align__(16) _Float16 lds[];   // 131072 B
  _Float16* As = lds;                // [2][256*64]
  _Float16* Bs = lds + 2 * 16384;    // [2][256*64]

  const int tid  = threadIdx.x;
  const int wave = tid >> 6, lane = tid & 63;

  // XCD-aware bijective swizzle over 1000 blocks (1000 % 8 == 0)
  const int d = blockIdx.x;
  const int g = (d & 7) * 125 + (d >> 3);
  const int row0 = (g >> 2) * 256;        // M panel (0..249)
  const int col0 = (g & 3) * 256;         // N panel (0..3)

  const int r = lane & 15, q = lane >> 4;
  const int wm = wave >> 2, wn = wave & 3;

  // --- staging addresses: i = j*512 + wave*64 + lane; row=i>>3, c=i&7.
  // LDS dest is linear (slot i); global source chunk is c ^ (row&7) so the
  // LDS slot (row,c) holds logical chunk c^(row&7). 16B chunks permute
  // within one 128B line -> coalescing preserved.
  int asrcB[4], bsrcB[4];
  int auoff[4];
#pragma unroll
  for (int j = 0; j < 4; ++j) {
    const int i   = j * 512 + wave * 64 + lane;
    const int row = i >> 3, c = i & 7;
    asrcB[j] = (row0 + row) * KA_ + ((c ^ (row & 7)) * 8);
    bsrcB[j] = (col0 + row) * KB_ + ((c ^ (row & 7)) * 8);
    auoff[j] = (j * 512 + wave * 64) * 8;   // wave-uniform LDS base (halfs)
  }

  // --- fragment read offsets (halfs). row&7 == r&7 for all frag rows.
  int aRow[8], bRow[4];
#pragma unroll
  for (int m = 0; m < 8; ++m) aRow[m] = (wm * 128 + m * 16 + r) * 64;
#pragma unroll
  for (int n = 0; n < 4; ++n) bRow[n] = (wn * 64 + n * 16 + r) * 64;
  const int sl0 = (q ^ (r & 7)) * 8;      // ks=0 slot (chunk q)
  const int sl1 = sl0 ^ 32;               // ks=1 slot (chunk q+4)

  f32x4 acc[8][4] = {};

  // --- prologue: stage K-step 0 into buf 0, drain, sync
#pragma unroll
  for (int j = 0; j < 4; ++j) gload16(A3 + asrcB[j], As + auoff[j]);
#pragma unroll
  for (int j = 0; j < 4; ++j) gload16(Bt + bsrcB[j], Bs + auoff[j]);
  asm volatile("s_waitcnt vmcnt(0)" ::: "memory");
  __syncthreads();

  for (int k = 0; k < NKSTEP_; ++k) {
    const int cbuf = (k & 1) * 16384;
    if (k + 1 < NKSTEP_) {
      const int k0n  = (k + 1) * 64;
      const int kAn  = (k0n < KA_) ? k0n : k0n - KA_;
      const int nbuf = ((k + 1) & 1) * 16384;
#pragma unroll
      for (int j = 0; j < 4; ++j)
        gload16(A3 + asrcB[j] + kAn, As + nbuf + auoff[j]);
#pragma unroll
      for (int j = 0; j < 4; ++j)
        gload16(Bt + bsrcB[j] + k0n, Bs + nbuf + auoff[j]);
      asm volatile("s_waitcnt vmcnt(8)" ::: "memory");
    } else {
      asm volatile("s_waitcnt vmcnt(0)" ::: "memory");
    }
    __builtin_amdgcn_sched_barrier(0);
    __builtin_amdgcn_s_barrier();              // B1
    __builtin_amdgcn_sched_barrier(0);

    {  // phase ks = 0
      half8 af[8], bf[4];
#pragma unroll
      for (int m = 0; m < 8; ++m)
        af[m] = *(const half8*)&As[cbuf + aRow[m] + sl0];
#pragma unroll
      for (int n = 0; n < 4; ++n)
        bf[n] = *(const half8*)&Bs[cbuf + bRow[n] + sl0];
      __builtin_amdgcn_s_setprio(1);
#pragma unroll
      for (int m = 0; m < 8; ++m)
#pragma unroll
        for (int n = 0; n < 4; ++n)
          acc[m][n] = __builtin_amdgcn_mfma_f32_16x16x32_f16(
              af[m], bf[n], acc[m][n], 0, 0, 0);
      __builtin_amdgcn_s_setprio(0);
    }
    {  // phase ks = 1
      half8 af[8], bf[4];
#pragma unroll
      for (int m = 0; m < 8; ++m)
        af[m] = *(const half8*)&As[cbuf + aRow[m] + sl1];
#pragma unroll
      for (int n = 0; n < 4; ++n)
        bf[n] = *(const half8*)&Bs[cbuf + bRow[n] + sl1];
      __builtin_amdgcn_s_setprio(1);
#pragma unroll
      for (int m = 0; m < 8; ++m)
#pragma unroll
        for (int n = 0; n < 4; ++n)
          acc[m][n] = __builtin_amdgcn_mfma_f32_16x16x32_f16(
              af[m], bf[n], acc[m][n], 0, 0, 0);
      __builtin_amdgcn_s_setprio(0);
    }
    __builtin_amdgcn_sched_barrier(0);
    __builtin_amdgcn_s_barrier();              // B2
    __builtin_amdgcn_sched_barrier(0);
  }

  // --- epilogue: C write (same layout as verified 128^2 kernel)
#pragma unroll
  for (int m = 0; m < 8; ++m) {
    const int mrow = row0 + wm * 128 + m * 16 + q * 4;
#pragma unroll
    for (int n = 0; n < 4; ++n) {
      const int ncol = col0 + wn * 64 + n * 16 + r;
      float* cp = Cm + (size_t)mrow * H_ + ncol;
#pragma unroll
      for (int rg = 0; rg < 4; ++rg)
        cp[(size_t)rg * H_] = acc[m][n][rg] * INV_SCALE2_;
    }
  }
}

// ---------------------------------------------------------------------------
// R8 recurrent (unchanged this round, for attribution): 4-wave column split,
// 256 threads per sample, spike bitmap exchanged via double-buffered LDS.
#define GATHER_LIF_STEP(NR, TCUR)                                             \
  {                                                                           \
    float Iv[4];                                                              \
    Iv[0] = NR.x; Iv[1] = NR.y; Iv[2] = NR.z; Iv[3] = NR.w;                   \
    float io = 0.f;                                                           \
    unsigned long long lm = __ballot(sword != 0u);                            \
    unsigned w = 0u;                                                          \
    int lcur = 0;                                                             \
    while ((lm != 0ull) | (w != 0u)) {                                        \
      int hA, hB, hC, hD;                                                     \
      float sB, sC, sD;                                                       \
      if (w == 0u) {                                                          \
        lcur = (int)__builtin_ctzll(lm); lm &= lm - 1ull;                     \
        w = ((unsigned)__builtin_amdgcn_readlane((int)sword, lcur)) & 0xFFFFu;\
      }                                                                       \
      hA = lcur * 16 + (int)__builtin_ctz(w); w &= w - 1u;                    \
      if (w == 0u && lm != 0ull) {                                            \
        lcur = (int)__builtin_ctzll(lm); lm &= lm - 1ull;                     \
        w = ((unsigned)__builtin_amdgcn_readlane((int)sword, lcur)) & 0xFFFFu;\
      }                                                                       \
      if (w != 0u) { hB = lcur*16 + (int)__builtin_ctz(w); w &= w-1u; sB=1.f;}\
      else         { hB = hA; sB = 0.f; }                                     \
      if (w == 0u && lm != 0ull) {                                            \
        lcur = (int)__builtin_ctzll(lm); lm &= lm - 1ull;                     \
        w = ((unsigned)__builtin_amdgcn_readlane((int)sword, lcur)) & 0xFFFFu;\
      }                                                                       \
      if (w != 0u) { hC = lcur*16 + (int)__builtin_ctz(w); w &= w-1u; sC=1.f;}\
      else         { hC = hA; sC = 0.f; }                                     \
      if (w == 0u && lm != 0ull) {                                            \
        lcur = (int)__builtin_ctzll(lm); lm &= lm - 1ull;                     \
        w = ((unsigned)__builtin_amdgcn_readlane((int)sword, lcur)) & 0xFFFFu;\
      }                                                                       \
      if (w != 0u) { hD = lcur*16 + (int)__builtin_ctz(w); w &= w-1u; sD=1.f;}\
      else         { hD = hA; sD = 0.f; }                                     \
      const float4 wA = *(const float4*)(wrecT + (size_t)hA * H_ + h0);       \
      const float4 wB = *(const float4*)(wrecT + (size_t)hB * H_ + h0);       \
      const float4 wC = *(const float4*)(wrecT + (size_t)hC * H_ + h0);       \
      const float4 wD = *(const float4*)(wrecT + (size_t)hD * H_ + h0);       \
      const float oA = woutT[(size_t)hA * O_ + olane];                        \
      const float oB = woutT[(size_t)hB * O_ + olane];                        \
      const float oC = woutT[(size_t)hC * O_ + olane];                        \
      const float oD = woutT[(size_t)hD * O_ + olane];                        \
      Iv[0] += wA.x; Iv[1] += wA.y; Iv[2] += wA.z; Iv[3] += wA.w;             \
      io += oA;                                                               \
      Iv[0] = fmaf(sB, wB.x, Iv[0]); Iv[1] = fmaf(sB, wB.y, Iv[1]);           \
      Iv[2] = fmaf(sB, wB.z, Iv[2]); Iv[3] = fmaf(sB, wB.w, Iv[3]);           \
      io = fmaf(sB, oB, io);                                                  \
      Iv[0] = fmaf(sC, wC.x, Iv[0]); Iv[1] = fmaf(sC, wC.y, Iv[1]);           \
      Iv[2] = fmaf(sC, wC.z, Iv[2]); Iv[3] = fmaf(sC, wC.w, Iv[3]);           \
      io = fmaf(sC, oC, io);                                                  \
      Iv[0] = fmaf(sD, wD.x, Iv[0]); Iv[1] = fmaf(sD, wD.y, Iv[1]);           \
      Iv[2] = fmaf(sD, wD.z, Iv[2]); Iv[3] = fmaf(sD, wD.w, Iv[3]);           \
      io = fmaf(sD, oD, io);                                                  \
    }                                                                         \
    {                                                                         \
      const int tp = ((TCUR) + 4 <= T_ - 1) ? (TCUR) + 4 : (T_ - 1);          \
      NR = *(const float4*)(base + (size_t)tp * (B_ * H_));                   \
    }                                                                         \
    vo = bo * vo + (1.0f - bo) * io;                                          \
    osum += vo;                                                               \
    unsigned nib = 0u;                                                        \
    _Pragma("unroll")                                                         \
    for (int j = 0; j < 4; ++j) {                                             \
      const float vg = (pnib & (1u << j)) ? 0.f : vv[j];                      \
      const float vn = al * vg + al1 * (Iv[j] - av[j]);                       \
      av[j] = rh * av[j] + rh1 * fmaf(ba, vn, (vn > 1.0f) ? 1.0f : 0.0f);     \
      vv[j] = vn;                                                             \
      nib |= (vn > 1.0f) ? (1u << j) : 0u;                                    \
    }                                                                         \
    pnib = nib;                                                               \
    spb[nbuf][tid] = (unsigned char)nib;                                      \
    __syncthreads();                                                          \
    {                                                                         \
      const unsigned w32 = *(const unsigned*)&spb[nbuf][lane * 4];            \
      sword = (w32 & 0xFu) | ((w32 >> 4) & 0xF0u) |                           \
              ((w32 >> 8) & 0xF00u) | ((w32 >> 12) & 0xF000u);                \
    }                                                                         \
    nbuf ^= 1;                                                                \
  }

__global__ __launch_bounds__(256, 1) void recurrent_w(
    const float* __restrict__ Iin,   // [M_][H_], row = t*128 + b
    const float* __restrict__ wrecT, // [H_][H_]  wrecT[h'][h] = w_rec[h][h']
    const float* __restrict__ woutT, // [H_][O_]  woutT[h][o]  = w_out[o][h]
    const float* __restrict__ alpha, const float* __restrict__ rho,
    const float* __restrict__ beta_a, const float* __restrict__ beta_out,
    float* __restrict__ out) {
  const int b    = blockIdx.x;
  const int tid  = threadIdx.x;     // 0..255
  const int lane = tid & 63;
  const int h0   = tid * 4;         // 4 columns per thread

  __shared__ unsigned char spb[2][256];   // double-buffered spike nibbles

  float vv[4], av[4];
#pragma unroll
  for (int j = 0; j < 4; ++j) { vv[j] = 0.f; av[j] = 0.f; }
  unsigned sword = 0u;   // full-bitmap slice: bit j = neuron lane*16+j @ prev
  unsigned pnib  = 0u;   // this thread's own 4 prev-spike bits
  int nbuf = 0;

  const float al = alpha[h0], al1 = 1.0f - al;
  const float rh = rho[h0],   rh1 = 1.0f - rh;
  const float ba = beta_a[h0];

  const int olane = (tid < O_) ? tid : 0;
  float bo = 0.f, vo = 0.f, osum = 0.f;
  if (tid < O_) bo = beta_out[tid];

  const float* base = Iin + (size_t)b * H_ + h0;

  // prime 4-deep prefetch pipeline: one float4 per t = 0,1,2,3
  float4 pA = *(const float4*)(base + (size_t)0 * (B_ * H_));
  float4 pB = *(const float4*)(base + (size_t)1 * (B_ * H_));
  float4 pC = *(const float4*)(base + (size_t)2 * (B_ * H_));
  float4 pD = *(const float4*)(base + (size_t)3 * (B_ * H_));

  for (int k = 0; k < T_ / 4; ++k) {
    const int t0 = k * 4;
    GATHER_LIF_STEP(pA, t0 + 0)
    GATHER_LIF_STEP(pB, t0 + 1)
    GATHER_LIF_STEP(pC, t0 + 2)
    GATHER_LIF_STEP(pD, t0 + 3)
  }

  // epilogue: readout contribution of the final spike set S(T-1)
  {
    float io = 0.f;
    unsigned long long lm = __ballot(sword != 0u);
    while (lm != 0ull) {
      const int l = (int)__builtin_ctzll(lm); lm &= lm - 1ull;
      unsigned w = ((unsigned)__builtin_amdgcn_readlane((int)sword, l)) & 0xFFFFu;
      while (w != 0u) {
        const int j = (int)__builtin_ctz(w); w &= w - 1u;
        io += woutT[(size_t)(l * 16 + j) * O_ + olane];
      }
    }
    vo = bo * vo + (1.0f - bo) * io;
    osum += vo;
  }

  if (tid < O_) out[(size_t)b * O_ + tid] = osum / (float)T_;
}

// ---------------------------------------------------------------------------
extern "C" void kernel_launch(void* const* d_in, const int* in_sizes, int n_in,
                              void* d_out, int out_size, void* d_ws, size_t ws_size,
                              hipStream_t stream) {
  const float* x        = (const float*)d_in[0];
  const int*   delays   = (const int*)d_in[1];
  const float* w_in     = (const float*)d_in[2];
  const float* w_rec    = (const float*)d_in[3];
  const float* w_out    = (const float*)d_in[4];
  const float* alpha    = (const float*)d_in[5];
  const float* rho      = (const float*)d_in[6];
  const float* beta_a   = (const float*)d_in[7];
  const float* beta_out = (const float*)d_in[8];

  float* ws    = (float*)d_ws;
  float* wrecT = ws;                                 // H*H fp32
  float* woutT = wrecT + (size_t)H_ * H_;            // H*O fp32
  float* Iin   = woutT + (size_t)H_ * O_;            // M*H fp32
  _Float16* A3 = (_Float16*)(Iin + (size_t)M_ * H_); // M*KA fp16
  _Float16* Bt = A3 + (size_t)M_ * KA_;              // H*KB fp16
  float* out   = (float*)d_out;

  transpose_pad<<<(H_ * H_) / 256, 256, 0, stream>>>(w_rec, wrecT, H_, H_, H_);
  transpose_pad<<<(H_ * O_) / 256, 256, 0, stream>>>(w_out, woutT, O_, H_, H_);
  bt_prep<<<(H_ * KB_) / 256, 256, 0, stream>>>(w_in, Bt);

  dim3 gd(B_, T_ / TT_, 2);   // (128, 25, 2)
  delay_split_lds<<<gd, 512, RR_ * LSTR_ * sizeof(float), stream>>>(x, delays, A3);

  // 256x256 tiles: (64000/256) * (1024/256) = 250 * 4 = 1000 blocks
  gemm_split<<<1000, 512, 131072, stream>>>(A3, Bt, Iin);

  recurrent_w<<<B_, 256, 0, stream>>>(Iin, wrecT, woutT,
                                      alpha, rho, beta_a, beta_out, out);
}

// Round 4
// 842.134 us; speedup vs baseline: 1.4603x; 1.0642x over previous
//
#include <hip/hip_runtime.h>
#include <stdint.h>

#define B_   128
#define T_   500
#define C_   700
#define CP_  704          // C padded to 16
#define H_   1024
#define O_   20
#define M_   (T_ * B_)    // 64000 rows, row = t*128 + b
#define KA_  (2 * CP_)    // 1408: A' = [hi | lo]
#define KB_  (3 * CP_)    // 2112: Bt = [hi | hi | lo]
#define NKSTEP_ (KB_ / 64)   // 33 K-steps of 64
#define SCALE_      256.0f
#define INV_SCALE2_ (1.0f / 65536.0f)
#define MAXD_ 30
#define TT_   20                       // t-rows produced per delay block
#define RR_   (TT_ + MAXD_)            // 50 source rows staged in LDS
#define CS_   176                      // channels per delay block (4-way split)
#define LSTR_ 180                      // LDS row stride: 720B = 16B-aligned,
                                       // 180%32=20 -> 8-position bank spread

typedef _Float16 half8 __attribute__((ext_vector_type(8)));
typedef float    f32x4 __attribute__((ext_vector_type(4)));

// ---------------------------------------------------------------------------
// out[c*R + r] = (c < C) ? in[r*C + c] : 0   (fp32 transpose, zero-pad)
__global__ __launch_bounds__(256) void transpose_pad(
    const float* __restrict__ in, float* __restrict__ out,
    int R, int C, int Cpad) {
  int idx = blockIdx.x * 256 + threadIdx.x;
  if (idx >= Cpad * R) return;
  int c = idx / R;
  int r = idx - c * R;
  out[idx] = (c < C) ? in[(size_t)r * C + c] : 0.0f;
}

// ---------------------------------------------------------------------------
// Bt[n][k]: k in [0,704) -> hi(w*256); [704,1408) -> hi; [1408,2112) -> lo
__global__ __launch_bounds__(256) void bt_prep(
    const float* __restrict__ w_in, _Float16* __restrict__ Bt) {
  int idx = blockIdx.x * 256 + threadIdx.x;   // over H_*KB_
  if (idx >= H_ * KB_) return;
  int n = idx / KB_;
  int k = idx - n * KB_;
  int blk = k / CP_;
  int c = k - blk * CP_;
  float v = (c < C_) ? w_in[(size_t)n * C_ + c] * SCALE_ : 0.0f;
  _Float16 hi = (_Float16)v;
  Bt[idx] = (blk == 2) ? (_Float16)(v - (float)hi) : hi;
}

// ---------------------------------------------------------------------------
// R10 delay gather: 4-way channel split (176 ch/block), LDS 50x180 fp32 =
// 36 KB -> 4 blocks/CU (R8's 70.6 KB gave only 2; suspected latency-bound).
// Row stride 180: rows stay 16B-aligned for float4 ds_writes; 180%32=20
// spreads gather rows over 8 bank positions (random delays do the rest).
__global__ __launch_bounds__(512) void delay_split_lds(
    const float* __restrict__ x, const int* __restrict__ delays,
    _Float16* __restrict__ A3) {
  extern __shared__ float xs[];          // [RR_][LSTR_] floats = 36000 B
  __shared__ int sdel[CS_];

  const int b   = blockIdx.x;            // 0..127
  const int t0  = blockIdx.y * TT_;      // 0,20,...,480
  const int c0  = blockIdx.z * CS_;      // 0,176,352,528
  const int tid = threadIdx.x;

  for (int c = tid; c < CS_; c += 512) {
    const int cc = c0 + c;
    sdel[c] = (cc < C_) ? delays[cc] : 0;
  }

  const int zr = (t0 < MAXD_) ? (MAXD_ - t0) : 0;
  const float* srcb = x + ((long)(b * T_ + t0) - MAXD_) * C_ + c0;
  for (int i = tid; i < RR_ * (CS_ / 4); i += 512) {
    const int r  = i / (CS_ / 4);
    const int q4 = (i - r * (CS_ / 4)) * 4;
    float4 v = {0.f, 0.f, 0.f, 0.f};
    if (r >= zr && c0 + q4 < C_)       // 700%4==0: chunks never straddle
      v = *(const float4*)(srcb + (long)r * C_ + q4);
    *(float4*)&xs[r * LSTR_ + q4] = v;
  }
  __syncthreads();

  for (int e = tid; e < TT_ * (CS_ / 8); e += 512) {
    const int tt = e / (CS_ / 8);
    const int cl = (e - tt * (CS_ / 8)) * 8;
    half8 hv, lv;
#pragma unroll
    for (int j = 0; j < 8; ++j) {
      const int c = cl + j;
      float vv = 0.f;
      if (c0 + c < C_)
        vv = xs[(tt + MAXD_ - sdel[c]) * LSTR_ + c] * SCALE_;
      const _Float16 hi = (_Float16)vv;
      hv[j] = hi;
      lv[j] = (_Float16)(vv - (float)hi);
    }
    _Float16* dst = A3 + (size_t)((t0 + tt) * B_ + b) * KA_ + c0 + cl;
    *(half8*)dst = hv;
    *((half8*)(dst + CP_)) = lv;
  }
}

// ---------------------------------------------------------------------------
__device__ __forceinline__ void gload16(const void* g, const void* l) {
  __builtin_amdgcn_global_load_lds(
      (const __attribute__((address_space(1))) void*)(uintptr_t)g,
      (__attribute__((address_space(3))) void*)(uint32_t)(uintptr_t)l,
      16, 0, 0);
}

// ---------------------------------------------------------------------------
// R11: 4-phase-per-K-tile schedule (m201 template port). Same geometry and
// addressing as R9 (256x256, BK=64, 8 waves 2Mx4N, T2 XOR-swizzle, XCD
// swizzle); only the sync structure changes. Per K-tile k:
//  P0: dsread quad(m0-3,ks0)+bf0 | stage A(k+1) x4 | bar | 16 MFMA | bar
//  P1: dsread quad(m4-7,ks0)     | stage B(k+1) h0 | bar | 16 MFMA | bar
//  P2: dsread quad(m0-3,ks1)+bf1 | stage B(k+1) h1 | bar | 16 MFMA | bar
//  P3: dsread quad(m4-7,ks1)     | vmcnt(0)(all stage >=1 phase old)
//                                               | bar | 16 MFMA | bar
// Race ledger: buf[(k+1)&1] written by stage[k+1] (issued P0..P2 of tile k)
// is first read at tile k+1's P0 dsread, which is after tile k P3's END
// barrier; every wave passed vmcnt(0) before that barrier -> writes landed.
// The buffer stage[k+1] overwrites was last ds_read at tile k-1 P3, whose
// values were consumed (lgkmcnt) before k-1's end barrier. setprio(T5) now
// has a role-split to arbitrate (null at 2-phase, +21-39% at per-phase).
__global__ __launch_bounds__(512, 1) void gemm_split(
    const _Float16* __restrict__ A3, const _Float16* __restrict__ Bt,
    float* __restrict__ Cm) {
  extern __shared__ __align__(16) _Float16 lds[];   // 131072 B
  _Float16* As = lds;                // [2][256*64]
  _Float16* Bs = lds + 2 * 16384;    // [2][256*64]

  const int tid  = threadIdx.x;
  const int wave = tid >> 6, lane = tid & 63;

  // XCD-aware bijective swizzle over 1000 blocks (1000 % 8 == 0)
  const int d = blockIdx.x;
  const int g = (d & 7) * 125 + (d >> 3);
  const int row0 = (g >> 2) * 256;        // M panel (0..249)
  const int col0 = (g & 3) * 256;         // N panel (0..3)

  const int r = lane & 15, q = lane >> 4;
  const int wm = wave >> 2, wn = wave & 3;

  // staging: i = j*512 + wave*64 + lane; row=i>>3, c=i&7. LDS dest linear;
  // global source chunk c^(row&7) (16B chunks permute within a 128B line).
  int asrcB[4], bsrcB[4], auoff[4];
#pragma unroll
  for (int j = 0; j < 4; ++j) {
    const int i   = j * 512 + wave * 64 + lane;
    const int row = i >> 3, c = i & 7;
    asrcB[j] = (row0 + row) * KA_ + ((c ^ (row & 7)) * 8);
    bsrcB[j] = (col0 + row) * KB_ + ((c ^ (row & 7)) * 8);
    auoff[j] = (j * 512 + wave * 64) * 8;   // wave-uniform LDS base (halfs)
  }

  // fragment read offsets (halfs); row&7 == r&7 for all frag rows.
  int aRow[8], bRow[4];
#pragma unroll
  for (int m = 0; m < 8; ++m) aRow[m] = (wm * 128 + m * 16 + r) * 64;
#pragma unroll
  for (int n = 0; n < 4; ++n) bRow[n] = (wn * 64 + n * 16 + r) * 64;
  const int sl0 = (q ^ (r & 7)) * 8;      // ks=0 slot
  const int sl1 = sl0 ^ 32;               // ks=1 slot

  f32x4 acc[8][4] = {};

  // prologue: stage K-tile 0 into buf 0, drain, sync
#pragma unroll
  for (int j = 0; j < 4; ++j) gload16(A3 + asrcB[j], As + auoff[j]);
#pragma unroll
  for (int j = 0; j < 4; ++j) gload16(Bt + bsrcB[j], Bs + auoff[j]);
  asm volatile("s_waitcnt vmcnt(0)" ::: "memory");
  __syncthreads();

#define PHASE_BAR() do {                                   \
    __builtin_amdgcn_sched_barrier(0);                     \
    __builtin_amdgcn_s_barrier();                          \
    __builtin_amdgcn_sched_barrier(0);                     \
  } while (0)

#define MFMA16(AF, BF) do {                                \
    __builtin_amdgcn_s_setprio(1);                         \
    _Pragma("unroll")                                      \
    for (int mm = 0; mm < 4; ++mm)                         \
      _Pragma("unroll")                                    \
      for (int nn = 0; nn < 4; ++nn)                       \
        ACCROW[mm][nn] = __builtin_amdgcn_mfma_f32_16x16x32_f16( \
            AF[mm], BF[nn], ACCROW[mm][nn], 0, 0, 0);      \
    __builtin_amdgcn_s_setprio(0);                         \
  } while (0)

  for (int k = 0; k < NKSTEP_; ++k) {
    const int cbuf = (k & 1) * 16384;
    const int nbuf = ((k + 1) & 1) * 16384;
    const int k0n  = (k + 1) * 64;
    const int kAn  = (k0n < KA_) ? k0n : k0n - KA_;
    const bool st  = (k + 1 < NKSTEP_);

    half8 a0[4], a1[4], b0[4], b1[4];

    // ---- P0: quad(m0-3, ks0); stage all 4 A-loads (HBM-prone, earliest)
#pragma unroll
    for (int m = 0; m < 4; ++m) a0[m] = *(const half8*)&As[cbuf + aRow[m] + sl0];
#pragma unroll
    for (int n = 0; n < 4; ++n) b0[n] = *(const half8*)&Bs[cbuf + bRow[n] + sl0];
    if (st) {
#pragma unroll
      for (int j = 0; j < 4; ++j) gload16(A3 + asrcB[j] + kAn, As + nbuf + auoff[j]);
    }
    PHASE_BAR();
    {
      f32x4 (&ACCROW)[4][4] = *reinterpret_cast<f32x4(*)[4][4]>(&acc[0]);
      MFMA16(a0, b0);
    }
    PHASE_BAR();

    // ---- P1: quad(m4-7, ks0); stage B half0
#pragma unroll
    for (int m = 0; m < 4; ++m) a1[m] = *(const half8*)&As[cbuf + aRow[m + 4] + sl0];
    if (st) {
      gload16(Bt + bsrcB[0] + k0n, Bs + nbuf + auoff[0]);
      gload16(Bt + bsrcB[1] + k0n, Bs + nbuf + auoff[1]);
    }
    PHASE_BAR();
    {
      f32x4 (&ACCROW)[4][4] = *reinterpret_cast<f32x4(*)[4][4]>(&acc[4]);
      MFMA16(a1, b0);
    }
    PHASE_BAR();

    // ---- P2: quad(m0-3, ks1); stage B half1
#pragma unroll
    for (int m = 0; m < 4; ++m) a0[m] = *(const half8*)&As[cbuf + aRow[m] + sl1];
#pragma unroll
    for (int n = 0; n < 4; ++n) b1[n] = *(const half8*)&Bs[cbuf + bRow[n] + sl1];
    if (st) {
      gload16(Bt + bsrcB[2] + k0n, Bs + nbuf + auoff[2]);
      gload16(Bt + bsrcB[3] + k0n, Bs + nbuf + auoff[3]);
    }
    PHASE_BAR();
    {
      f32x4 (&ACCROW)[4][4] = *reinterpret_cast<f32x4(*)[4][4]>(&acc[0]);
      MFMA16(a0, b1);
    }
    PHASE_BAR();

    // ---- P3: quad(m4-7, ks1); drain stage (all loads >=1 phase old)
#pragma unroll
    for (int m = 0; m < 4; ++m) a1[m] = *(const half8*)&As[cbuf + aRow[m + 4] + sl1];
    PHASE_BAR();
    {
      f32x4 (&ACCROW)[4][4] = *reinterpret_cast<f32x4(*)[4][4]>(&acc[4]);
      MFMA16(a1, b1);
    }
    asm volatile("s_waitcnt vmcnt(0)" ::: "memory");
    PHASE_BAR();   // cross-tile barrier: all waves' stage writes landed
  }
#undef MFMA16
#undef PHASE_BAR

  // epilogue: C write (unchanged layout)
#pragma unroll
  for (int m = 0; m < 8; ++m) {
    const int mrow = row0 + wm * 128 + m * 16 + q * 4;
#pragma unroll
    for (int n = 0; n < 4; ++n) {
      const int ncol = col0 + wn * 64 + n * 16 + r;
      float* cp = Cm + (size_t)mrow * H_ + ncol;
#pragma unroll
      for (int rg = 0; rg < 4; ++rg)
        cp[(size_t)rg * H_] = acc[m][n][rg] * INV_SCALE2_;
    }
  }
}

// ---------------------------------------------------------------------------
// R8 recurrent (unchanged this round, control): 4-wave column split,
// 256 threads per sample, spike bitmap exchanged via double-buffered LDS.
#define GATHER_LIF_STEP(NR, TCUR)                                             \
  {                                                                           \
    float Iv[4];                                                              \
    Iv[0] = NR.x; Iv[1] = NR.y; Iv[2] = NR.z; Iv[3] = NR.w;                   \
    float io = 0.f;                                                           \
    unsigned long long lm = __ballot(sword != 0u);                            \
    unsigned w = 0u;                                                          \
    int lcur = 0;                                                             \
    while ((lm != 0ull) | (w != 0u)) {                                        \
      int hA, hB, hC, hD;                                                     \
      float sB, sC, sD;                                                       \
      if (w == 0u) {                                                          \
        lcur = (int)__builtin_ctzll(lm); lm &= lm - 1ull;                     \
        w = ((unsigned)__builtin_amdgcn_readlane((int)sword, lcur)) & 0xFFFFu;\
      }                                                                       \
      hA = lcur * 16 + (int)__builtin_ctz(w); w &= w - 1u;                    \
      if (w == 0u && lm != 0ull) {                                            \
        lcur = (int)__builtin_ctzll(lm); lm &= lm - 1ull;                     \
        w = ((unsigned)__builtin_amdgcn_readlane((int)sword, lcur)) & 0xFFFFu;\
      }                                                                       \
      if (w != 0u) { hB = lcur*16 + (int)__builtin_ctz(w); w &= w-1u; sB=1.f;}\
      else         { hB = hA; sB = 0.f; }                                     \
      if (w == 0u && lm != 0ull) {                                            \
        lcur = (int)__builtin_ctzll(lm); lm &= lm - 1ull;                     \
        w = ((unsigned)__builtin_amdgcn_readlane((int)sword, lcur)) & 0xFFFFu;\
      }                                                                       \
      if (w != 0u) { hC = lcur*16 + (int)__builtin_ctz(w); w &= w-1u; sC=1.f;}\
      else         { hC = hA; sC = 0.f; }                                     \
      if (w == 0u && lm != 0ull) {                                            \
        lcur = (int)__builtin_ctzll(lm); lm &= lm - 1ull;                     \
        w = ((unsigned)__builtin_amdgcn_readlane((int)sword, lcur)) & 0xFFFFu;\
      }                                                                       \
      if (w != 0u) { hD = lcur*16 + (int)__builtin_ctz(w); w &= w-1u; sD=1.f;}\
      else         { hD = hA; sD = 0.f; }                                     \
      const float4 wA = *(const float4*)(wrecT + (size_t)hA * H_ + h0);       \
      const float4 wB = *(const float4*)(wrecT + (size_t)hB * H_ + h0);       \
      const float4 wC = *(const float4*)(wrecT + (size_t)hC * H_ + h0);       \
      const float4 wD = *(const float4*)(wrecT + (size_t)hD * H_ + h0);       \
      const float oA = woutT[(size_t)hA * O_ + olane];                        \
      const float oB = woutT[(size_t)hB * O_ + olane];                        \
      const float oC = woutT[(size_t)hC * O_ + olane];                        \
      const float oD = woutT[(size_t)hD * O_ + olane];                        \
      Iv[0] += wA.x; Iv[1] += wA.y; Iv[2] += wA.z; Iv[3] += wA.w;             \
      io += oA;                                                               \
      Iv[0] = fmaf(sB, wB.x, Iv[0]); Iv[1] = fmaf(sB, wB.y, Iv[1]);           \
      Iv[2] = fmaf(sB, wB.z, Iv[2]); Iv[3] = fmaf(sB, wB.w, Iv[3]);           \
      io = fmaf(sB, oB, io);                                                  \
      Iv[0] = fmaf(sC, wC.x, Iv[0]); Iv[1] = fmaf(sC, wC.y, Iv[1]);           \
      Iv[2] = fmaf(sC, wC.z, Iv[2]); Iv[3] = fmaf(sC, wC.w, Iv[3]);           \
      io = fmaf(sC, oC, io);                                                  \
      Iv[0] = fmaf(sD, wD.x, Iv[0]); Iv[1] = fmaf(sD, wD.y, Iv[1]);           \
      Iv[2] = fmaf(sD, wD.z, Iv[2]); Iv[3] = fmaf(sD, wD.w, Iv[3]);           \
      io = fmaf(sD, oD, io);                                                  \
    }                                                                         \
    {                                                                         \
      const int tp = ((TCUR) + 4 <= T_ - 1) ? (TCUR) + 4 : (T_ - 1);          \
      NR = *(const float4*)(base + (size_t)tp * (B_ * H_));                   \
    }                                                                         \
    vo = bo * vo + (1.0f - bo) * io;                                          \
    osum += vo;                                                               \
    unsigned nib = 0u;                                                        \
    _Pragma("unroll")                                                         \
    for (int j = 0; j < 4; ++j) {                                             \
      const float vg = (pnib & (1u << j)) ? 0.f : vv[j];                      \
      const float vn = al * vg + al1 * (Iv[j] - av[j]);                       \
      av[j] = rh * av[j] + rh1 * fmaf(ba, vn, (vn > 1.0f) ? 1.0f : 0.0f);     \
      vv[j] = vn;                                                             \
      nib |= (vn > 1.0f) ? (1u << j) : 0u;                                    \
    }                                                                         \
    pnib = nib;                                                               \
    spb[nbuf][tid] = (unsigned char)nib;                                      \
    __syncthreads();                                                          \
    {                                                                         \
      const unsigned w32 = *(const unsigned*)&spb[nbuf][lane * 4];            \
      sword = (w32 & 0xFu) | ((w32 >> 4) & 0xF0u) |                           \
              ((w32 >> 8) & 0xF00u) | ((w32 >> 12) & 0xF000u);                \
    }                                                                         \
    nbuf ^= 1;                                                                \
  }

__global__ __launch_bounds__(256, 1) void recurrent_w(
    const float* __restrict__ Iin,   // [M_][H_], row = t*128 + b
    const float* __restrict__ wrecT, // [H_][H_]  wrecT[h'][h] = w_rec[h][h']
    const float* __restrict__ woutT, // [H_][O_]  woutT[h][o]  = w_out[o][h]
    const float* __restrict__ alpha, const float* __restrict__ rho,
    const float* __restrict__ beta_a, const float* __restrict__ beta_out,
    float* __restrict__ out) {
  const int b    = blockIdx.x;
  const int tid  = threadIdx.x;     // 0..255
  const int lane = tid & 63;
  const int h0   = tid * 4;         // 4 columns per thread

  __shared__ unsigned char spb[2][256];   // double-buffered spike nibbles

  float vv[4], av[4];
#pragma unroll
  for (int j = 0; j < 4; ++j) { vv[j] = 0.f; av[j] = 0.f; }
  unsigned sword = 0u;   // full-bitmap slice: bit j = neuron lane*16+j @ prev
  unsigned pnib  = 0u;   // this thread's own 4 prev-spike bits
  int nbuf = 0;

  const float al = alpha[h0], al1 = 1.0f - al;
  const float rh = rho[h0],   rh1 = 1.0f - rh;
  const float ba = beta_a[h0];

  const int olane = (tid < O_) ? tid : 0;
  float bo = 0.f, vo = 0.f, osum = 0.f;
  if (tid < O_) bo = beta_out[tid];

  const float* base = Iin + (size_t)b * H_ + h0;

  // prime 4-deep prefetch pipeline: one float4 per t = 0,1,2,3
  float4 pA = *(const float4*)(base + (size_t)0 * (B_ * H_));
  float4 pB = *(const float4*)(base + (size_t)1 * (B_ * H_));
  float4 pC = *(const float4*)(base + (size_t)2 * (B_ * H_));
  float4 pD = *(const float4*)(base + (size_t)3 * (B_ * H_));

  for (int k = 0; k < T_ / 4; ++k) {
    const int t0 = k * 4;
    GATHER_LIF_STEP(pA, t0 + 0)
    GATHER_LIF_STEP(pB, t0 + 1)
    GATHER_LIF_STEP(pC, t0 + 2)
    GATHER_LIF_STEP(pD, t0 + 3)
  }

  // epilogue: readout contribution of the final spike set S(T-1)
  {
    float io = 0.f;
    unsigned long long lm = __ballot(sword != 0u);
    while (lm != 0ull) {
      const int l = (int)__builtin_ctzll(lm); lm &= lm - 1ull;
      unsigned w = ((unsigned)__builtin_amdgcn_readlane((int)sword, l)) & 0xFFFFu;
      while (w != 0u) {
        const int j = (int)__builtin_ctz(w); w &= w - 1u;
        io += woutT[(size_t)(l * 16 + j) * O_ + olane];
      }
    }
    vo = bo * vo + (1.0f - bo) * io;
    osum += vo;
  }

  if (tid < O_) out[(size_t)b * O_ + tid] = osum / (float)T_;
}

// ---------------------------------------------------------------------------
extern "C" void kernel_launch(void* const* d_in, const int* in_sizes, int n_in,
                              void* d_out, int out_size, void* d_ws, size_t ws_size,
                              hipStream_t stream) {
  const float* x        = (const float*)d_in[0];
  const int*   delays   = (const int*)d_in[1];
  const float* w_in     = (const float*)d_in[2];
  const float* w_rec    = (const float*)d_in[3];
  const float* w_out    = (const float*)d_in[4];
  const float* alpha    = (const float*)d_in[5];
  const float* rho      = (const float*)d_in[6];
  const float* beta_a   = (const float*)d_in[7];
  const float* beta_out = (const float*)d_in[8];

  float* ws    = (float*)d_ws;
  float* wrecT = ws;                                 // H*H fp32
  float* woutT = wrecT + (size_t)H_ * H_;            // H*O fp32
  float* Iin   = woutT + (size_t)H_ * O_;            // M*H fp32
  _Float16* A3 = (_Float16*)(Iin + (size_t)M_ * H_); // M*KA fp16
  _Float16* Bt = A3 + (size_t)M_ * KA_;              // H*KB fp16
  float* out   = (float*)d_out;

  transpose_pad<<<(H_ * H_) / 256, 256, 0, stream>>>(w_rec, wrecT, H_, H_, H_);
  transpose_pad<<<(H_ * O_) / 256, 256, 0, stream>>>(w_out, woutT, O_, H_, H_);
  bt_prep<<<(H_ * KB_) / 256, 256, 0, stream>>>(w_in, Bt);

  dim3 gd(B_, T_ / TT_, 4);   // (128, 25, 4)
  delay_split_lds<<<gd, 512, RR_ * LSTR_ * sizeof(float), stream>>>(x, delays, A3);

  // 256x256 tiles: (64000/256) * (1024/256) = 250 * 4 = 1000 blocks
  gemm_split<<<1000, 512, 131072, stream>>>(A3, Bt, Iin);

  recurrent_w<<<B_, 256, 0, stream>>>(Iin, wrecT, woutT,
                                      alpha, rho, beta_a, beta_out, out);
}